// Round 23
// baseline (69.472 us; speedup 1.0000x reference)
//
#include <hip/hip_runtime.h>
#include <hip/hip_bf16.h>
#include <math.h>

#define B 4
#define T 4096
#define C 1024
#define HS 64

typedef __attribute__((ext_vector_type(8))) short short8;
typedef __attribute__((ext_vector_type(4))) float f32x4;
typedef __attribute__((ext_vector_type(16))) float f32x16;

#define MFMA16(a, b, c) __builtin_amdgcn_mfma_f32_16x16x32_bf16((a), (b), (c), 0, 0, 0)
#define MFMA32(a, b, c) __builtin_amdgcn_mfma_f32_32x32x16_bf16((a), (b), (c), 0, 0, 0)

// Q pre-scale: C^-0.5 * log2(e)  (softmax computed in 2^x domain)
#define QSCALE 0.0450842200278f

static __device__ __forceinline__ unsigned short f2bf(float f) {
  union { float f; unsigned u; } v; v.f = f;
  unsigned r = v.u + 0x7FFFu + ((v.u >> 16) & 1u);  // RNE to bf16
  return (unsigned short)(r >> 16);
}

static __device__ __forceinline__ unsigned pack_bf2(float lo, float hi2) {
  union { __hip_bfloat16 h; unsigned short u; } a, c;
  a.h = __float2bfloat16(lo); c.h = __float2bfloat16(hi2);
  return (unsigned)a.u | ((unsigned)c.u << 16);
}

// ---------------------------------------------------------------------------
// Kernel 0: W -> bf16 FRAGMENT-READY Wtf (round-17, verified).
// ---------------------------------------------------------------------------
__global__ __launch_bounds__(256) void conv_w_kernel(
    const float* __restrict__ Wq, const float* __restrict__ Wk,
    const float* __restrict__ Wv, unsigned short* __restrict__ Wtf) {
  const int wi = blockIdx.x >> 4;          // 0..2
  const int c0 = (blockIdx.x & 15) * 64;
  const float* W = (wi == 0) ? Wq : (wi == 1) ? Wk : Wv;
  __shared__ float ws[64][65];
  const int t = threadIdx.x;
  const int r = t >> 2;                    // c-row within chunk
  const int cb = (t & 3) * 16;             // h-col base
#pragma unroll
  for (int j = 0; j < 4; ++j) {
    const f32x4 v = *(const f32x4*)&W[(size_t)(c0 + r) * HS + cb + 4 * j];
    ws[cb + 4 * j + 0][r] = v[0];
    ws[cb + 4 * j + 1][r] = v[1];
    ws[cb + 4 * j + 2][r] = v[2];
    ws[cb + 4 * j + 3][r] = v[3];
  }
  __syncthreads();
  const int h  = t >> 2;                   // n within this W (0..63)
  const int rb = (t & 3) * 16;             // c base within chunk
  const int n   = wi * 64 + h;
  const int nt  = n >> 4;
  const int col = n & 15;
#pragma unroll
  for (int j = 0; j < 2; ++j) {
    const int cbase = c0 + rb + j * 8;     // 8-aligned
    union { short8 s8; unsigned short u[8]; } o;
#pragma unroll
    for (int e = 0; e < 8; ++e) o.u[e] = f2bf(ws[h][rb + j * 8 + e]);
    const int kc128 = cbase >> 7;
    const int k32   = (cbase >> 5) & 3;
    const int grp   = (cbase >> 3) & 3;
    const size_t idx =
        ((size_t)(kc128 * 48 + k32 * 12 + nt) * 512 + (grp * 16 + col) * 8);
    *(short8*)(Wtf + idx) = o.s8;
  }
}

// ---------------------------------------------------------------------------
// Kernel 1: fused QKV projection GEMM, v7 — BARRIER-FREE main loop.
// B fragments load DIRECT Wtf->VGPR (contiguous 1KB bursts, L2-resident);
// A loads direct x->VGPR (32B/lane contiguous; 4-way wn redundancy dedups
// in L1). No LDS, no __syncthreads in the K-loop -> no vmcnt(0) drains.
// 16 K-steps of 64; 1-deep named-buffer prefetch; per-block phase skew.
// Epilogue: round-20 LDS-staged coalesced fragment stores (own 24KB).
// ---------------------------------------------------------------------------
__global__ __launch_bounds__(512, 2) void proj_kernel(
    const float* __restrict__ x, const unsigned short* __restrict__ Wtf,
    const float* __restrict__ bq, const float* __restrict__ bk,
    const float* __restrict__ bv,
    unsigned short* __restrict__ Qf, unsigned short* __restrict__ Kf,
    unsigned short* __restrict__ Vf) {
  const int m0   = blockIdx.x * 64;
  const int w    = threadIdx.x >> 6;   // 0..7
  const int lane = threadIdx.x & 63;
  const int col  = lane & 15, grp = lane >> 4;
  const int wm   = w >> 2;             // 0..1: row half (32 rows)
  const int wn   = w & 3;              // 0..3: col group (48 cols)
  const int phase = blockIdx.x & 15;

  __shared__ unsigned short E_lds[2][12][512];   // 24 KB epilogue staging

  f32x4 acc[2][3];
#pragma unroll
  for (int mf = 0; mf < 2; ++mf)
#pragma unroll
    for (int jj = 0; jj < 3; ++jj) acc[mf][jj] = (f32x4){0.f, 0.f, 0.f, 0.f};

  auto kcOf = [&](int it) { return ((it + phase) & 15) * 64; };

  // A: lane's 8 fp32 per (mf,k32) fragment; 8 f32x4 per step.
  auto loadA = [&](int kc, f32x4 (&af)[8]) {
#pragma unroll
    for (int mf = 0; mf < 2; ++mf)
#pragma unroll
      for (int k32 = 0; k32 < 2; ++k32) {
        const float* p = x + (size_t)(m0 + wm * 32 + mf * 16 + col) * C +
                         kc + k32 * 32 + grp * 8;
        af[(mf * 2 + k32) * 2 + 0] = *(const f32x4*)p;
        af[(mf * 2 + k32) * 2 + 1] = *(const f32x4*)(p + 4);
      }
  };
  // B: this wave's 6 fragments, contiguous 16B/lane bursts.
  auto loadB = [&](int kc, short8 (&bf)[6]) {
    const int kc128 = kc >> 7;
    const int k32b  = (kc >> 5) & 3;   // 0 or 2
#pragma unroll
    for (int k32 = 0; k32 < 2; ++k32)
#pragma unroll
      for (int jj = 0; jj < 3; ++jj)
        bf[k32 * 3 + jj] = *(const short8*)(
            Wtf + ((size_t)(kc128 * 48 + (k32b + k32) * 12 + wn * 3 + jj) * 512)
                + lane * 8);
  };
  auto cvtA = [&](const f32x4 (&af)[8], short8 (&a)[4]) {
#pragma unroll
    for (int i = 0; i < 4; ++i) {
      short8 t;
#pragma unroll
      for (int e = 0; e < 4; ++e) {
        t[e]     = (short)f2bf(af[2 * i][e]);
        t[4 + e] = (short)f2bf(af[2 * i + 1][e]);
      }
      a[i] = t;
    }
  };
  auto compute = [&](const short8 (&a)[4], const short8 (&bf)[6]) {
#pragma unroll
    for (int mf = 0; mf < 2; ++mf)
#pragma unroll
      for (int k32 = 0; k32 < 2; ++k32)
#pragma unroll
        for (int jj = 0; jj < 3; ++jj)
          acc[mf][jj] = MFMA16(a[mf * 2 + k32], bf[k32 * 3 + jj], acc[mf][jj]);
  };

  f32x4 afA[8], afB[8];
  short8 bfA[6], bfB[6];
  short8 a[4];

  loadA(kcOf(0), afA);
  loadB(kcOf(0), bfA);
  for (int it = 0; it < 16; it += 2) {
    loadA(kcOf(it + 1), afB);          // prefetch odd step
    loadB(kcOf(it + 1), bfB);
    cvtA(afA, a);
    compute(a, bfA);
    if (it + 2 < 16) {
      loadA(kcOf(it + 2), afA);        // prefetch next even step
      loadB(kcOf(it + 2), bfA);
    }
    cvtA(afB, a);
    compute(a, bfB);
  }

  // ---- epilogue: stage through LDS in fragment layout, store 1KB bursts
#pragma unroll
  for (int mf = 0; mf < 2; ++mf) {
#pragma unroll
    for (int jj = 0; jj < 3; ++jj) {
      const int n = wn * 48 + jj * 16 + col;
      const float bias = (n < 64) ? bq[n] : (n < 128) ? bk[n - 64] : bv[n - 128];
#pragma unroll
      for (int r = 0; r < 4; ++r) {
        const int rloc = mf * 16 + 4 * grp + r;     // row within 32-row blk
        const float v = acc[mf][jj][r] + bias;      // blk_local = wm
        if (n < 64) {
          E_lds[wm][n >> 4][(((n >> 3) & 1) * 32 + rloc) * 8 + (n & 7)] =
              f2bf(v * QSCALE);
        } else if (n < 128) {
          const int d = n - 64;
          E_lds[wm][4 + (d >> 4)][(((d >> 3) & 1) * 32 + rloc) * 8 + (d & 7)] =
              f2bf(v);
        } else {
          const int d = n - 128;
          const int vi = ((d >> 5) << 1) + ((rloc >> 4) & 1);
          E_lds[wm][8 + vi][(((rloc >> 3) & 1) * 32 + (d & 31)) * 8 + (rloc & 7)] =
              f2bf(v);
        }
      }
    }
  }
  __syncthreads();

  {
    const int bb    = m0 >> 12;
    const int blkg0 = (m0 & (T - 1)) >> 5;
#pragma unroll
    for (int j = 0; j < 3; ++j) {
      const int fidx  = w * 3 + j;        // 0..23
      const int blk_l = fidx / 12;
      const int ft    = fidx % 12;
      const short8 val = *(const short8*)&E_lds[blk_l][ft][lane * 8];
      const size_t fb = ((size_t)(bb * 128 + blkg0 + blk_l) * 4);
      unsigned short* dst;
      if (ft < 4)      dst = Qf + (fb + ft) * 512;
      else if (ft < 8) dst = Kf + (fb + (ft - 4)) * 512;
      else             dst = Vf + (fb + (ft - 8)) * 512;
      *(short8*)(dst + lane * 8) = val;
    }
  }
}

// ---------------------------------------------------------------------------
// Kernel 2: flash attention, far-pair + permlane (round-20, verified best).
// ---------------------------------------------------------------------------
__global__ __launch_bounds__(512, 2) void attn_kernel(
    const unsigned short* __restrict__ Qf,
    const unsigned short* __restrict__ Kf,
    const unsigned short* __restrict__ Vf,
    float* __restrict__ out) {
  const int x8 = blockIdx.x & 7;
  const int b  = x8 >> 1;
  const int p  = ((blockIdx.x >> 3) << 1) | (x8 & 1);   // 0..63

  const int w8   = threadIdx.x >> 6;   // 0..7
  const int g    = w8 >> 2;            // group 0/1
  const int w    = w8 & 3;             // wave within group
  const int lane = threadIdx.x & 63;
  const int q    = lane & 31;
  const int hi   = lane >> 5;          // 0..1
  const int qt   = g ? (127 - p) : p;  // this group's q-tile
  const int qbase = qt * 32;
  const int qg    = qbase + q;

  __shared__ float accL[8][64][33];    // 67.6 KB
  __shared__ float lL[8][32], invL[2][32];

  const unsigned short* Qp = Qf + ((size_t)(b * 128 + qt) * 4) * 512;
  const unsigned short* Kb = Kf + ((size_t)b * 128) * 4 * 512;
  const unsigned short* Vb = Vf + ((size_t)b * 128) * 4 * 512;

  short8 qf[4];
#pragma unroll
  for (int j = 0; j < 4; ++j)
    qf[j] = *(const short8*)(Qp + j * 512 + lane * 8);

  f32x16 acc0, acc1;
#pragma unroll
  for (int r = 0; r < 16; ++r) { acc0[r] = 0.f; acc1[r] = 0.f; }
  float lsum = 0.f;

  const int nkv = qt + 1;

  short8 kA[4], vA[4], kB[4], vB[4];

  auto loadKV = [&](int kb, short8 (&kd)[4], short8 (&vd)[4]) {
    const unsigned short* pk = Kb + (size_t)kb * 2048 + lane * 8;
    kd[0] = *(const short8*)(pk);
    kd[1] = *(const short8*)(pk + 512);
    kd[2] = *(const short8*)(pk + 1024);
    kd[3] = *(const short8*)(pk + 1536);
    const unsigned short* pv = Vb + (size_t)kb * 2048 + lane * 8;
    vd[0] = *(const short8*)(pv);
    vd[1] = *(const short8*)(pv + 512);
    vd[2] = *(const short8*)(pv + 1024);
    vd[3] = *(const short8*)(pv + 1536);
  };

  auto step = [&](int kb, short8 (&kc)[4], short8 (&vc)[4],
                  short8 (&kn)[4], short8 (&vn)[4]) {
    int knb = kb + 4;                  // this wave's next kb
    if (knb > 127) knb = 127;
    loadKV(knb, kn, vn);

    f32x16 s;
#pragma unroll
    for (int r = 0; r < 16; ++r) s[r] = -8.0f;
    s = MFMA32(kc[0], qf[0], s);
    s = MFMA32(kc[1], qf[1], s);
    s = MFMA32(kc[2], qf[2], s);
    s = MFMA32(kc[3], qf[3], s);

    float pe[16];
    if (kb == qt) {                    // diagonal block: causal mask
      const int qrel = qg - kb * 32;
#pragma unroll
      for (int r = 0; r < 16; ++r) {
        const int key = (r & 3) + 8 * (r >> 2) + 4 * hi;
        const float v = exp2f(s[r]);
        pe[r] = (key <= qrel) ? v : 0.f;
      }
    } else {
#pragma unroll
      for (int r = 0; r < 16; ++r) pe[r] = exp2f(s[r]);
    }
#pragma unroll
    for (int r = 0; r < 16; ++r) lsum += pe[r];

    unsigned own[8];
#pragma unroll
    for (int j = 0; j < 8; ++j) own[j] = pack_bf2(pe[2 * j], pe[2 * j + 1]);
    unsigned a0v = own[0], b0v = own[2];
    unsigned a1v = own[1], b1v = own[3];
    unsigned a2v = own[4], b2v = own[6];
    unsigned a3v = own[5], b3v = own[7];
    asm("v_permlane32_swap_b32 %0, %1" : "+v"(a0v), "+v"(b0v));
    asm("v_permlane32_swap_b32 %0, %1" : "+v"(a1v), "+v"(b1v));
    asm("v_permlane32_swap_b32 %0, %1" : "+v"(a2v), "+v"(b2v));
    asm("v_permlane32_swap_b32 %0, %1" : "+v"(a3v), "+v"(b3v));
    union U { short8 s8; unsigned u[4]; };
    U p0, p1;
    p0.u[0] = a0v; p0.u[1] = a1v; p0.u[2] = b0v; p0.u[3] = b1v;
    p1.u[0] = a2v; p1.u[1] = a3v; p1.u[2] = b2v; p1.u[3] = b3v;

    acc0 = MFMA32(vc[0], p0.s8, acc0);
    acc0 = MFMA32(vc[1], p1.s8, acc0);
    acc1 = MFMA32(vc[2], p0.s8, acc1);
    acc1 = MFMA32(vc[3], p1.s8, acc1);
  };

  if (w < nkv) {
    loadKV(w, kA, vA);
    int kb = w;
    while (true) {
      step(kb, kA, vA, kB, vB); kb += 4; if (kb >= nkv) break;
      step(kb, kB, vB, kA, vA); kb += 4; if (kb >= nkv) break;
    }
  }

  lsum += __shfl_xor(lsum, 32, 64);
  if (hi == 0) lL[w8][q] = lsum;
#pragma unroll
  for (int r = 0; r < 16; ++r) {
    const int d = (r & 3) + 8 * (r >> 2) + 4 * hi;
    accL[w8][d][q]      = acc0[r];
    accL[w8][d + 32][q] = acc1[r];
  }
  __syncthreads();
  if (threadIdx.x < 64) {
    const int g2 = threadIdx.x >> 5;
    const int qq = threadIdx.x & 31;
    const float L = lL[g2 * 4 + 0][qq] + lL[g2 * 4 + 1][qq] +
                    lL[g2 * 4 + 2][qq] + lL[g2 * 4 + 3][qq];
    invL[g2][qq] = 1.f / L;
  }
  __syncthreads();
  {
    const int tid2 = threadIdx.x & 255;
#pragma unroll
    for (int pp = 0; pp < 8; ++pp) {
      const int qq = (tid2 >> 6) + 4 * pp;
      const int d  = tid2 & 63;
      const float v = accL[g * 4 + 0][d][qq] + accL[g * 4 + 1][d][qq] +
                      accL[g * 4 + 2][d][qq] + accL[g * 4 + 3][d][qq];
      out[(size_t)(b * T + qbase + qq) * HS + d] = v * invL[g][qq];
    }
  }
}

extern "C" void kernel_launch(void* const* d_in, const int* in_sizes, int n_in,
                              void* d_out, int out_size, void* d_ws, size_t ws_size,
                              hipStream_t stream) {
  const float* x  = (const float*)d_in[0];
  const float* Wq = (const float*)d_in[1];
  const float* bq = (const float*)d_in[2];
  const float* Wk = (const float*)d_in[3];
  const float* bk = (const float*)d_in[4];
  const float* Wv = (const float*)d_in[5];
  const float* bv = (const float*)d_in[6];
  float* out = (float*)d_out;

  unsigned short* Qf  = (unsigned short*)d_ws;
  unsigned short* Kf  = Qf + (size_t)B * T * HS;
  unsigned short* Vf  = Kf + (size_t)B * T * HS;
  unsigned short* Wtf = Vf + (size_t)B * T * HS;

  conv_w_kernel<<<48, 256, 0, stream>>>(Wq, Wk, Wv, Wtf);
  proj_kernel<<<B * T / 64, 512, 0, stream>>>(x, Wtf, bq, bk, bv, Qf, Kf, Vf);
  attn_kernel<<<B * 64, 512, 0, stream>>>(Qf, Kf, Vf, out);
}

// Round 24
// 49.543 us; speedup vs baseline: 1.4023x; 1.4023x over previous
//
#include <hip/hip_runtime.h>
#include <hip/hip_bf16.h>
#include <math.h>

#define B 4
#define T 4096
#define C 1024
#define HS 64

typedef __attribute__((ext_vector_type(8))) short short8;
typedef __attribute__((ext_vector_type(4))) float f32x4;
typedef __attribute__((ext_vector_type(16))) float f32x16;

#define MFMA16(a, b, c) __builtin_amdgcn_mfma_f32_16x16x32_bf16((a), (b), (c), 0, 0, 0)
#define MFMA32(a, b, c) __builtin_amdgcn_mfma_f32_32x32x16_bf16((a), (b), (c), 0, 0, 0)

// Q pre-scale: C^-0.5 * log2(e)  (softmax computed in 2^x domain)
#define QSCALE 0.0450842200278f

static __device__ __forceinline__ unsigned short f2bf(float f) {
  union { float f; unsigned u; } v; v.f = f;
  unsigned r = v.u + 0x7FFFu + ((v.u >> 16) & 1u);  // RNE to bf16
  return (unsigned short)(r >> 16);
}

static __device__ __forceinline__ unsigned pack_bf2(float lo, float hi2) {
  union { __hip_bfloat16 h; unsigned short u; } a, c;
  a.h = __float2bfloat16(lo); c.h = __float2bfloat16(hi2);
  return (unsigned)a.u | ((unsigned)c.u << 16);
}

// ---------------------------------------------------------------------------
// Kernel 0: W -> bf16 FRAGMENT-READY Wtf (round-17, verified).
// ---------------------------------------------------------------------------
__global__ __launch_bounds__(256) void conv_w_kernel(
    const float* __restrict__ Wq, const float* __restrict__ Wk,
    const float* __restrict__ Wv, unsigned short* __restrict__ Wtf) {
  const int wi = blockIdx.x >> 4;          // 0..2
  const int c0 = (blockIdx.x & 15) * 64;
  const float* W = (wi == 0) ? Wq : (wi == 1) ? Wk : Wv;
  __shared__ float ws[64][65];
  const int t = threadIdx.x;
  const int r = t >> 2;                    // c-row within chunk
  const int cb = (t & 3) * 16;             // h-col base
#pragma unroll
  for (int j = 0; j < 4; ++j) {
    const f32x4 v = *(const f32x4*)&W[(size_t)(c0 + r) * HS + cb + 4 * j];
    ws[cb + 4 * j + 0][r] = v[0];
    ws[cb + 4 * j + 1][r] = v[1];
    ws[cb + 4 * j + 2][r] = v[2];
    ws[cb + 4 * j + 3][r] = v[3];
  }
  __syncthreads();
  const int h  = t >> 2;                   // n within this W (0..63)
  const int rb = (t & 3) * 16;             // c base within chunk
  const int n   = wi * 64 + h;
  const int nt  = n >> 4;
  const int col = n & 15;
#pragma unroll
  for (int j = 0; j < 2; ++j) {
    const int cbase = c0 + rb + j * 8;     // 8-aligned
    union { short8 s8; unsigned short u[8]; } o;
#pragma unroll
    for (int e = 0; e < 8; ++e) o.u[e] = f2bf(ws[h][rb + j * 8 + e]);
    const int kc128 = cbase >> 7;
    const int k32   = (cbase >> 5) & 3;
    const int grp   = (cbase >> 3) & 3;
    const size_t idx =
        ((size_t)(kc128 * 48 + k32 * 12 + nt) * 512 + (grp * 16 + col) * 8);
    *(short8*)(Wtf + idx) = o.s8;
  }
}

// ---------------------------------------------------------------------------
// Kernel 1: fused QKV projection GEMM (round-20: R17 core + LDS-staged
// coalesced epilogue; verified best).
// ---------------------------------------------------------------------------
__global__ __launch_bounds__(512, 2) void proj_kernel(
    const float* __restrict__ x, const unsigned short* __restrict__ Wtf,
    const float* __restrict__ bq, const float* __restrict__ bk,
    const float* __restrict__ bv,
    unsigned short* __restrict__ Qf, unsigned short* __restrict__ Kf,
    unsigned short* __restrict__ Vf) {
  const int m0   = blockIdx.x * 64;
  const int w    = threadIdx.x >> 6;   // 0..7
  const int lane = threadIdx.x & 63;
  const int col  = lane & 15, grp = lane >> 4;
  const int wm   = w >> 2;             // 0..1: row half (32 rows)
  const int wn   = w & 3;              // 0..3: col group (48 cols)
  const int phase = blockIdx.x & 7;

  __shared__ unsigned short A_lds[2][64 * 128];   // 32 KB, XOR-swizzled rows
  __shared__ unsigned short B_lds[2][48][512];    // 96 KB, frag-ordered

  const int arow  = threadIdx.x >> 3;
  const int akoff = (threadIdx.x & 7) * 16;
  const float* xp = x + (size_t)(m0 + arow) * C + akoff;

  f32x4 acc[2][3];
#pragma unroll
  for (int mf = 0; mf < 2; ++mf)
#pragma unroll
    for (int jj = 0; jj < 3; ++jj) acc[mf][jj] = (f32x4){0.f, 0.f, 0.f, 0.f};

  auto kcOf = [&](int it) { return ((it + phase) & 7) * 128; };

  auto stageB = [&](int nb, int kc) {
    const int kc128 = kc >> 7;
#pragma unroll
    for (int j = 0; j < 6; ++j) {
      const int f = w * 6 + j;
      const unsigned short* src =
          Wtf + ((size_t)(kc128 * 48 + f) * 512) + lane * 8;
      __builtin_amdgcn_global_load_lds(
          (const __attribute__((address_space(1))) void*)src,
          (__attribute__((address_space(3))) void*)&B_lds[nb][f][0],
          16, 0, 0);
    }
  };

  auto loadAreg = [&](int kc, f32x4 (&r)[4]) {
#pragma unroll
    for (int i = 0; i < 4; ++i) r[i] = *(const f32x4*)(xp + kc + 4 * i);
  };

  auto writeA = [&](int nb, const f32x4 (&r)[4]) {
    union { short8 s8[2]; unsigned short u[16]; } o;
#pragma unroll
    for (int i = 0; i < 4; ++i)
#pragma unroll
      for (int e = 0; e < 4; ++e) o.u[4 * i + e] = f2bf(r[i][e]);
    const int b0 = arow * 256 + (threadIdx.x & 7) * 32;   // byte offset
    const int s  = (arow & 7) << 4;                        // XOR swizzle
    char* base = (char*)&A_lds[nb][0];
    *(short8*)(base + ((b0     ) ^ s)) = o.s8[0];
    *(short8*)(base + ((b0 + 16) ^ s)) = o.s8[1];
  };

  auto readA = [&](int buf, int mf, int k32) {
    const int row = wm * 32 + mf * 16 + col;
    const int b = row * 256 + ((k32 * 64 + grp * 16) ^ ((col & 7) << 4));
    return *(const short8*)((const char*)&A_lds[buf][0] + b);
  };

  auto compute = [&](int buf) {
#pragma unroll
    for (int k32 = 0; k32 < 4; ++k32) {
      const short8 a0 = readA(buf, 0, k32);
      const short8 a1 = readA(buf, 1, k32);
#pragma unroll
      for (int jj = 0; jj < 3; ++jj) {
        const short8 bf =
            *(const short8*)&B_lds[buf][k32 * 12 + wn * 3 + jj][(size_t)lane * 8];
        acc[0][jj] = MFMA16(a0, bf, acc[0][jj]);
        acc[1][jj] = MFMA16(a1, bf, acc[1][jj]);
      }
    }
  };

  f32x4 arA[4];
  loadAreg(kcOf(0), arA);
  stageB(0, kcOf(0));
  writeA(0, arA);
  loadAreg(kcOf(1), arA);
  __syncthreads();

  for (int it = 0; it < 8; ++it) {
    const int buf = it & 1;
    if (it < 7) stageB(buf ^ 1, kcOf(it + 1));
    compute(buf);
    if (it < 7) {
      writeA(buf ^ 1, arA);
      if (it < 6) loadAreg(kcOf(it + 2), arA);
    }
    __syncthreads();
  }

  // ---- epilogue v2: stage through LDS in fragment layout, store 1KB bursts
  unsigned short (*E)[12][512] =
      (unsigned short (*)[12][512]) & A_lds[0][0];   // 24 KB reuse

#pragma unroll
  for (int mf = 0; mf < 2; ++mf) {
#pragma unroll
    for (int jj = 0; jj < 3; ++jj) {
      const int n = wn * 48 + jj * 16 + col;
      const float bias = (n < 64) ? bq[n] : (n < 128) ? bk[n - 64] : bv[n - 128];
#pragma unroll
      for (int r = 0; r < 4; ++r) {
        const int rloc = mf * 16 + 4 * grp + r;     // row within 32-row blk
        const float v = acc[mf][jj][r] + bias;      // blk_local = wm
        if (n < 64) {
          E[wm][n >> 4][(((n >> 3) & 1) * 32 + rloc) * 8 + (n & 7)] =
              f2bf(v * QSCALE);
        } else if (n < 128) {
          const int d = n - 64;
          E[wm][4 + (d >> 4)][(((d >> 3) & 1) * 32 + rloc) * 8 + (d & 7)] =
              f2bf(v);
        } else {
          const int d = n - 128;
          const int vi = ((d >> 5) << 1) + ((rloc >> 4) & 1);
          E[wm][8 + vi][(((rloc >> 3) & 1) * 32 + (d & 31)) * 8 + (rloc & 7)] =
              f2bf(v);
        }
      }
    }
  }
  __syncthreads();

  {
    const int bb    = m0 >> 12;
    const int blkg0 = (m0 & (T - 1)) >> 5;
#pragma unroll
    for (int j = 0; j < 3; ++j) {
      const int fidx  = w * 3 + j;        // 0..23
      const int blk_l = fidx / 12;
      const int ft    = fidx % 12;
      const short8 val = *(const short8*)&E[blk_l][ft][lane * 8];
      const size_t fb = ((size_t)(bb * 128 + blkg0 + blk_l) * 4);
      unsigned short* dst;
      if (ft < 4)      dst = Qf + (fb + ft) * 512;
      else if (ft < 8) dst = Kf + (fb + (ft - 4)) * 512;
      else             dst = Vf + (fb + (ft - 8)) * 512;
      *(short8*)(dst + lane * 8) = val;
    }
  }
}

// ---------------------------------------------------------------------------
// Kernel 2: flash attention, far-pair + fixed-offset exp2 softmax +
// permlane32_swap exchange (round-20, verified best).
// ---------------------------------------------------------------------------
__global__ __launch_bounds__(512, 2) void attn_kernel(
    const unsigned short* __restrict__ Qf,
    const unsigned short* __restrict__ Kf,
    const unsigned short* __restrict__ Vf,
    float* __restrict__ out) {
  const int x8 = blockIdx.x & 7;
  const int b  = x8 >> 1;
  const int p  = ((blockIdx.x >> 3) << 1) | (x8 & 1);   // 0..63

  const int w8   = threadIdx.x >> 6;   // 0..7
  const int g    = w8 >> 2;            // group 0/1
  const int w    = w8 & 3;             // wave within group
  const int lane = threadIdx.x & 63;
  const int q    = lane & 31;
  const int hi   = lane >> 5;          // 0..1
  const int qt   = g ? (127 - p) : p;  // this group's q-tile
  const int qbase = qt * 32;
  const int qg    = qbase + q;

  __shared__ float accL[8][64][33];    // 67.6 KB
  __shared__ float lL[8][32], invL[2][32];

  const unsigned short* Qp = Qf + ((size_t)(b * 128 + qt) * 4) * 512;
  const unsigned short* Kb = Kf + ((size_t)b * 128) * 4 * 512;
  const unsigned short* Vb = Vf + ((size_t)b * 128) * 4 * 512;

  short8 qf[4];
#pragma unroll
  for (int j = 0; j < 4; ++j)
    qf[j] = *(const short8*)(Qp + j * 512 + lane * 8);

  f32x16 acc0, acc1;
#pragma unroll
  for (int r = 0; r < 16; ++r) { acc0[r] = 0.f; acc1[r] = 0.f; }
  float lsum = 0.f;

  const int nkv = qt + 1;

  short8 kA[4], vA[4], kB[4], vB[4];

  auto loadKV = [&](int kb, short8 (&kd)[4], short8 (&vd)[4]) {
    const unsigned short* pk = Kb + (size_t)kb * 2048 + lane * 8;
    kd[0] = *(const short8*)(pk);
    kd[1] = *(const short8*)(pk + 512);
    kd[2] = *(const short8*)(pk + 1024);
    kd[3] = *(const short8*)(pk + 1536);
    const unsigned short* pv = Vb + (size_t)kb * 2048 + lane * 8;
    vd[0] = *(const short8*)(pv);
    vd[1] = *(const short8*)(pv + 512);
    vd[2] = *(const short8*)(pv + 1024);
    vd[3] = *(const short8*)(pv + 1536);
  };

  auto step = [&](int kb, short8 (&kc)[4], short8 (&vc)[4],
                  short8 (&kn)[4], short8 (&vn)[4]) {
    int knb = kb + 4;                  // this wave's next kb
    if (knb > 127) knb = 127;
    loadKV(knb, kn, vn);

    f32x16 s;
#pragma unroll
    for (int r = 0; r < 16; ++r) s[r] = -8.0f;
    s = MFMA32(kc[0], qf[0], s);
    s = MFMA32(kc[1], qf[1], s);
    s = MFMA32(kc[2], qf[2], s);
    s = MFMA32(kc[3], qf[3], s);

    float pe[16];
    if (kb == qt) {                    // diagonal block: causal mask
      const int qrel = qg - kb * 32;
#pragma unroll
      for (int r = 0; r < 16; ++r) {
        const int key = (r & 3) + 8 * (r >> 2) + 4 * hi;
        const float v = exp2f(s[r]);
        pe[r] = (key <= qrel) ? v : 0.f;
      }
    } else {
#pragma unroll
      for (int r = 0; r < 16; ++r) pe[r] = exp2f(s[r]);
    }
#pragma unroll
    for (int r = 0; r < 16; ++r) lsum += pe[r];

    unsigned own[8];
#pragma unroll
    for (int j = 0; j < 8; ++j) own[j] = pack_bf2(pe[2 * j], pe[2 * j + 1]);
    unsigned a0v = own[0], b0v = own[2];
    unsigned a1v = own[1], b1v = own[3];
    unsigned a2v = own[4], b2v = own[6];
    unsigned a3v = own[5], b3v = own[7];
    asm("v_permlane32_swap_b32 %0, %1" : "+v"(a0v), "+v"(b0v));
    asm("v_permlane32_swap_b32 %0, %1" : "+v"(a1v), "+v"(b1v));
    asm("v_permlane32_swap_b32 %0, %1" : "+v"(a2v), "+v"(b2v));
    asm("v_permlane32_swap_b32 %0, %1" : "+v"(a3v), "+v"(b3v));
    union U { short8 s8; unsigned u[4]; };
    U p0, p1;
    p0.u[0] = a0v; p0.u[1] = a1v; p0.u[2] = b0v; p0.u[3] = b1v;
    p1.u[0] = a2v; p1.u[1] = a3v; p1.u[2] = b2v; p1.u[3] = b3v;

    acc0 = MFMA32(vc[0], p0.s8, acc0);
    acc0 = MFMA32(vc[1], p1.s8, acc0);
    acc1 = MFMA32(vc[2], p0.s8, acc1);
    acc1 = MFMA32(vc[3], p1.s8, acc1);
  };

  if (w < nkv) {
    loadKV(w, kA, vA);
    int kb = w;
    while (true) {
      step(kb, kA, vA, kB, vB); kb += 4; if (kb >= nkv) break;
      step(kb, kB, vB, kA, vA); kb += 4; if (kb >= nkv) break;
    }
  }

  lsum += __shfl_xor(lsum, 32, 64);
  if (hi == 0) lL[w8][q] = lsum;
#pragma unroll
  for (int r = 0; r < 16; ++r) {
    const int d = (r & 3) + 8 * (r >> 2) + 4 * hi;
    accL[w8][d][q]      = acc0[r];
    accL[w8][d + 32][q] = acc1[r];
  }
  __syncthreads();
  if (threadIdx.x < 64) {
    const int g2 = threadIdx.x >> 5;
    const int qq = threadIdx.x & 31;
    const float L = lL[g2 * 4 + 0][qq] + lL[g2 * 4 + 1][qq] +
                    lL[g2 * 4 + 2][qq] + lL[g2 * 4 + 3][qq];
    invL[g2][qq] = 1.f / L;
  }
  __syncthreads();
  {
    const int tid2 = threadIdx.x & 255;
#pragma unroll
    for (int pp = 0; pp < 8; ++pp) {
      const int qq = (tid2 >> 6) + 4 * pp;
      const int d  = tid2 & 63;
      const float v = accL[g * 4 + 0][d][qq] + accL[g * 4 + 1][d][qq] +
                      accL[g * 4 + 2][d][qq] + accL[g * 4 + 3][d][qq];
      out[(size_t)(b * T + qbase + qq) * HS + d] = v * invL[g][qq];
    }
  }
}

extern "C" void kernel_launch(void* const* d_in, const int* in_sizes, int n_in,
                              void* d_out, int out_size, void* d_ws, size_t ws_size,
                              hipStream_t stream) {
  const float* x  = (const float*)d_in[0];
  const float* Wq = (const float*)d_in[1];
  const float* bq = (const float*)d_in[2];
  const float* Wk = (const float*)d_in[3];
  const float* bk = (const float*)d_in[4];
  const float* Wv = (const float*)d_in[5];
  const float* bv = (const float*)d_in[6];
  float* out = (float*)d_out;

  unsigned short* Qf  = (unsigned short*)d_ws;
  unsigned short* Kf  = Qf + (size_t)B * T * HS;
  unsigned short* Vf  = Kf + (size_t)B * T * HS;
  unsigned short* Wtf = Vf + (size_t)B * T * HS;

  conv_w_kernel<<<48, 256, 0, stream>>>(Wq, Wk, Wv, Wtf);
  proj_kernel<<<B * T / 64, 512, 0, stream>>>(x, Wtf, bq, bk, bv, Qf, Kf, Vf);
  attn_kernel<<<B * 64, 512, 0, stream>>>(Qf, Kf, Vf, out);
}